// Round 11
// baseline (435.243 us; speedup 1.0000x reference)
//
#include <hip/hip_runtime.h>
#include <hip/hip_cooperative_groups.h>

namespace cg = cooperative_groups;

typedef unsigned short u16;
typedef __bf16 bf16x8 __attribute__((ext_vector_type(8)));
typedef float f32x4 __attribute__((ext_vector_type(4)));

#define D 64
#define LPITCH 136   // 128 + 8 bf16 pad
#define CHUNKS 256   // edge-array partitions == grid size of coop kernel
#define BSHIFT 9     // 512 nodes per bucket (nbuck <= 256 for N <= 131072)

__device__ __forceinline__ float b2f(u16 u) {
    unsigned v = ((unsigned)u) << 16;
    float f;
    __builtin_memcpy(&f, &v, 4);
    return f;
}
__device__ __forceinline__ float u2f_lo(unsigned u) {
    unsigned v = u << 16;
    float f;
    __builtin_memcpy(&f, &v, 4);
    return f;
}
__device__ __forceinline__ float u2f_hi(unsigned u) {
    unsigned v = u & 0xFFFF0000u;
    float f;
    __builtin_memcpy(&f, &v, 4);
    return f;
}
__device__ __forceinline__ u16 f2b(float f) {
    unsigned u;
    __builtin_memcpy(&u, &f, 4);
    u = u + 0x7FFFu + ((u >> 16) & 1u);   // RNE
    return (u16)(u >> 16);
}
__device__ __forceinline__ bf16x8 ld_frag(const u16* p) {
    union { uint4 u; bf16x8 b; } cv;
    cv.u = *(const uint4*)p;
    return cv.b;
}

// ---------------- one cooperative kernel: binned CSR build + cvt + weight prep -------
// 256 blocks x 256 threads (1 block/CU -> co-residency guaranteed). Phases separated
// by grid.sync(). No global atomics anywhere (R4/R5 lesson: scattered global atomics
// cost ~32B HBM traffic each).
struct CsrArgs {
    const int* dst;
    const int* src;
    int E, N, nbuck, eper, total4;
    int* H;
    int* Orel;
    int* T;
    int* base;
    int* row_ptr;
    float* inv_deg;
    int* staging;
    int* col;
    const float* xf;
    const float* wl;
    const float* wr;
    const float* wres;
    const float* wfc;
    u16* xb;
    u16* WtL;
    u16* WresT;
    u16* WfcT;
};

__global__ __launch_bounds__(256) void csr_kernel(CsrArgs a) {
    __shared__ union {
        int hist[256];
        struct { int cnt[512]; int lrp[512]; int sm[256]; } c;
    } sh;
    cg::grid_group grid = cg::this_grid();
    int t = threadIdx.x;
    int c = blockIdx.x;

    // ---- phase A: per-chunk bucket histogram ----
    sh.hist[t] = 0;
    __syncthreads();
    {
        int beg = c * a.eper, end = min(beg + a.eper, a.E);
        for (int i = beg + t; i < end; i += 256)
            atomicAdd(&sh.hist[a.dst[i] >> BSHIFT], 1);
    }
    __syncthreads();
    if (t < a.nbuck) a.H[c * a.nbuck + t] = sh.hist[t];
    grid.sync();

    // ---- phase S2: per-bucket scan over chunk counts -> Orel + bucket total T ----
    if (c < a.nbuck) {
        int h = a.H[t * a.nbuck + c];
        sh.hist[t] = h;
        __syncthreads();
        for (int off = 1; off < 256; off <<= 1) {
            int v = (t >= off) ? sh.hist[t - off] : 0;
            __syncthreads();
            sh.hist[t] += v;
            __syncthreads();
        }
        a.Orel[t * a.nbuck + c] = sh.hist[t] - h;   // exclusive
        if (t == 255) a.T[c] = sh.hist[255];
    }
    grid.sync();

    // ---- phase T: block 0 scans bucket totals -> base[]; row_ptr[N] ----
    if (c == 0) {
        int v = (t < a.nbuck) ? a.T[t] : 0;
        sh.hist[t] = v;
        __syncthreads();
        for (int off = 1; off < 256; off <<= 1) {
            int u = (t >= off) ? sh.hist[t - off] : 0;
            __syncthreads();
            sh.hist[t] += u;
            __syncthreads();
        }
        if (t < a.nbuck) a.base[t] = sh.hist[t] - v;
        if (t == 255) {
            a.base[a.nbuck] = sh.hist[255];
            a.row_ptr[a.N] = sh.hist[255];
        }
    }
    grid.sync();

    // ---- phase B: scatter packed (src | local_dst<<17) into bucket-grouped staging --
    {
        if (t < a.nbuck) sh.hist[t] = a.base[t] + a.Orel[c * a.nbuck + t];
        __syncthreads();
        int beg = c * a.eper, end = min(beg + a.eper, a.E);
        const int mask = (1 << BSHIFT) - 1;
        for (int i = beg + t; i < end; i += 256) {
            int d = a.dst[i];
            int b = d >> BSHIFT;
            int p = atomicAdd(&sh.hist[b], 1);
            a.staging[p] = a.src[i] | ((d & mask) << 17);
        }
    }
    grid.sync();

    // ---- phase C: block per bucket; degree hist + local scan + col scatter in LDS ----
    if (c < a.nbuck) {
        int node0 = c << BSHIFT;
        int nn = min(1 << BSHIFT, a.N - node0);
        sh.c.cnt[t] = 0;
        sh.c.cnt[t + 256] = 0;
        __syncthreads();
        int sbeg = a.base[c], send = a.base[c + 1];
        for (int i = sbeg + t; i < send; i += 256)
            atomicAdd(&sh.c.cnt[a.staging[i] >> 17], 1);
        __syncthreads();
        int c0 = sh.c.cnt[2 * t], c1 = sh.c.cnt[2 * t + 1];
        sh.c.sm[t] = c0 + c1;
        __syncthreads();
        for (int off = 1; off < 256; off <<= 1) {
            int v = (t >= off) ? sh.c.sm[t - off] : 0;
            __syncthreads();
            sh.c.sm[t] += v;
            __syncthreads();
        }
        int excl = sh.c.sm[t] - c0 - c1;
        sh.c.lrp[2 * t] = excl;
        sh.c.lrp[2 * t + 1] = excl + c0;
        __syncthreads();
        for (int i = t; i < nn; i += 256) {
            a.row_ptr[node0 + i] = sbeg + sh.c.lrp[i];
            int dd = sh.c.cnt[i];
            a.inv_deg[node0 + i] = dd > 0 ? 1.0f / (float)dd : 0.0f;
        }
        __syncthreads();
        for (int i = sbeg + t; i < send; i += 256) {
            int word = a.staging[i];
            int ld = word >> 17;
            int k = atomicSub(&sh.c.cnt[ld], 1) - 1;
            a.col[sbeg + sh.c.lrp[ld] + k] = word & 0x1FFFF;
        }
    }

    // ---- tail (no sync needed: consumed only by later dispatches): cvt + weight prep --
    {
        int gid = c * 256 + t;
        int gstr = 256 * 256;
        for (int i = gid; i < a.total4; i += gstr) {
            float4 v = *(const float4*)(a.xf + i * 4);
            ushort4 o;
            o.x = f2b(v.x); o.y = f2b(v.y); o.z = f2b(v.z); o.w = f2b(v.w);
            *(ushort4*)(a.xb + i * 4) = o;
        }
        for (int idx = gid; idx < 3 * 64 * 128; idx += gstr) {
            int l = idx >> 13;
            int rem = idx & 8191;
            int n = rem >> 7;
            int k = rem & 127;
            float v = (k < 64) ? a.wl[l * 4096 + k * 64 + n]
                               : a.wr[l * 4096 + (k - 64) * 64 + n];
            a.WtL[idx] = f2b(v);
        }
        for (int idx = gid; idx < 4096; idx += gstr) {
            int n = idx >> 6, k = idx & 63;
            a.WresT[idx] = f2b(a.wres[k * 64 + n]);
            a.WfcT[idx] = f2b(a.wfc[k * 64 + n]);
        }
    }
}

// ---------------- fused SAGE layer: gather-mean + GEMM + LN + ReLU + residual --------
// R9 config (best measured): 256 threads, 4 waves, static slot-per-node, 8-deep gather,
// sB LDS-staged weights (R7: global-weight B-frags thrash L1).
__global__ __launch_bounds__(256, 4) void layer_kernel(const u16* __restrict__ xb_in,
                                                       const int* __restrict__ row_ptr,
                                                       const int* __restrict__ col,
                                                       const float* __restrict__ inv_deg,
                                                       const u16* __restrict__ Wt,    // [64][128]
                                                       const float* __restrict__ bl,
                                                       const float* __restrict__ gam,
                                                       const float* __restrict__ bet,
                                                       const u16* __restrict__ WresT, // [64][64]
                                                       const float* __restrict__ bres,
                                                       const u16* __restrict__ WfcT,  // [64][64]
                                                       const float* __restrict__ bfc,
                                                       u16* __restrict__ xb_out,
                                                       float* __restrict__ fout,
                                                       int N, int layer0, int final_) {
    __shared__ __align__(16) u16 sA[64 * LPITCH];
    __shared__ __align__(16) u16 sB[64 * LPITCH];
    int tid = threadIdx.x;
    int base = blockIdx.x * 64;
    int lane = tid & 63;
    int w = tid >> 6;

    // stage B (W^T rows), 4 uint4 per thread
#pragma unroll
    for (int i = 0; i < 4; i++) {
        int idx = i * 256 + tid;
        int r = idx >> 4, c = idx & 15;
        *(uint4*)&sB[r * LPITCH + c * 8] = *(const uint4*)(Wt + idx * 8);
    }
    // stage x rows into sA cols 64..127, 2 uint4 per thread
#pragma unroll
    for (int i = 0; i < 2; i++) {
        int idx = i * 256 + tid;
        int r = idx >> 3, c = idx & 7;
        int node = base + r;
        uint4 v = make_uint4(0, 0, 0, 0);
        if (node < N) v = *(const uint4*)(xb_in + node * D + c * 8);
        *(uint4*)&sA[r * LPITCH + 64 + c * 8] = v;
    }

    // gather stage: slot-per-node, 2 rounds x 8 slots per wave = 16 nodes/wave
    int slot = lane >> 3;
    int chunk = lane & 7;
#pragma unroll
    for (int r = 0; r < 2; r++) {
        int node_l = w * 16 + r * 8 + slot;
        int node = base + node_l;
        float a0 = 0, a1 = 0, a2 = 0, a3 = 0, a4 = 0, a5 = 0, a6 = 0, a7 = 0;
        uint4 o = make_uint4(0, 0, 0, 0);
        if (node < N) {
            int e = row_ptr[node], end = row_ptr[node + 1];
#define ACC(v)                                          \
    a0 += u2f_lo(v.x); a1 += u2f_hi(v.x);               \
    a2 += u2f_lo(v.y); a3 += u2f_hi(v.y);               \
    a4 += u2f_lo(v.z); a5 += u2f_hi(v.z);               \
    a6 += u2f_lo(v.w); a7 += u2f_hi(v.w);
            for (; e + 7 < end; e += 8) {       // 8 row-gathers in flight per slot
                int s0 = col[e],     s1 = col[e + 1], s2 = col[e + 2], s3 = col[e + 3];
                int s4 = col[e + 4], s5 = col[e + 5], s6 = col[e + 6], s7 = col[e + 7];
                uint4 v0 = *(const uint4*)(xb_in + s0 * D + chunk * 8);
                uint4 v1 = *(const uint4*)(xb_in + s1 * D + chunk * 8);
                uint4 v2 = *(const uint4*)(xb_in + s2 * D + chunk * 8);
                uint4 v3 = *(const uint4*)(xb_in + s3 * D + chunk * 8);
                uint4 v4 = *(const uint4*)(xb_in + s4 * D + chunk * 8);
                uint4 v5 = *(const uint4*)(xb_in + s5 * D + chunk * 8);
                uint4 v6 = *(const uint4*)(xb_in + s6 * D + chunk * 8);
                uint4 v7 = *(const uint4*)(xb_in + s7 * D + chunk * 8);
                ACC(v0) ACC(v1) ACC(v2) ACC(v3)
                ACC(v4) ACC(v5) ACC(v6) ACC(v7)
            }
            if (e + 3 < end) {
                int s0 = col[e], s1 = col[e + 1], s2 = col[e + 2], s3 = col[e + 3];
                uint4 v0 = *(const uint4*)(xb_in + s0 * D + chunk * 8);
                uint4 v1 = *(const uint4*)(xb_in + s1 * D + chunk * 8);
                uint4 v2 = *(const uint4*)(xb_in + s2 * D + chunk * 8);
                uint4 v3 = *(const uint4*)(xb_in + s3 * D + chunk * 8);
                ACC(v0) ACC(v1) ACC(v2) ACC(v3)
                e += 4;
            }
            if (e + 1 < end) {
                int s0 = col[e], s1 = col[e + 1];
                uint4 v0 = *(const uint4*)(xb_in + s0 * D + chunk * 8);
                uint4 v1 = *(const uint4*)(xb_in + s1 * D + chunk * 8);
                ACC(v0) ACC(v1)
                e += 2;
            }
            if (e < end) {
                int s0 = col[e];
                uint4 v0 = *(const uint4*)(xb_in + s0 * D + chunk * 8);
                ACC(v0)
            }
#undef ACC
            float m = inv_deg[node];
            o.x = (unsigned)f2b(a0 * m) | ((unsigned)f2b(a1 * m) << 16);
            o.y = (unsigned)f2b(a2 * m) | ((unsigned)f2b(a3 * m) << 16);
            o.z = (unsigned)f2b(a4 * m) | ((unsigned)f2b(a5 * m) << 16);
            o.w = (unsigned)f2b(a6 * m) | ((unsigned)f2b(a7 * m) << 16);
        }
        *(uint4*)&sA[node_l * LPITCH + chunk * 8] = o;
    }
    __syncthreads();

    // GEMM stage
    int q = lane >> 4;
    int ln = lane & 15;
    f32x4 acc[4] = {{0, 0, 0, 0}, {0, 0, 0, 0}, {0, 0, 0, 0}, {0, 0, 0, 0}};
    f32x4 accr[4] = {{0, 0, 0, 0}, {0, 0, 0, 0}, {0, 0, 0, 0}, {0, 0, 0, 0}};
    const u16* aRow = &sA[(w * 16 + ln) * LPITCH];

#pragma unroll
    for (int c = 0; c < 4; c++) {       // K = 128
        bf16x8 a = ld_frag(&aRow[c * 32 + q * 8]);
#pragma unroll
        for (int t = 0; t < 4; t++) {
            bf16x8 b = ld_frag(&sB[(t * 16 + ln) * LPITCH + c * 32 + q * 8]);
            acc[t] = __builtin_amdgcn_mfma_f32_16x16x32_bf16(a, b, acc[t], 0, 0, 0);
        }
    }
    if (layer0) {                       // residual = x @ w_res (8 one-shot global loads)
#pragma unroll
        for (int c = 0; c < 2; c++) {
            bf16x8 a = ld_frag(&aRow[64 + c * 32 + q * 8]);
#pragma unroll
            for (int t = 0; t < 4; t++) {
                bf16x8 b = ld_frag(WresT + (t * 16 + ln) * 64 + c * 32 + q * 8);
                accr[t] = __builtin_amdgcn_mfma_f32_16x16x32_bf16(a, b, accr[t], 0, 0, 0);
            }
        }
    }

    float bcol[4], gcol[4], btcol[4], brcol[4];
#pragma unroll
    for (int t = 0; t < 4; t++) {
        int colI = t * 16 + ln;
        bcol[t] = bl[colI];
        gcol[t] = gam[colI];
        btcol[t] = bet[colI];
        brcol[t] = layer0 ? bres[colI] : 0.f;
    }
#pragma unroll
    for (int t = 0; t < 4; t++)
#pragma unroll
        for (int r = 0; r < 4; r++) acc[t][r] += bcol[t];

    float ps[4], pq[4];
#pragma unroll
    for (int r = 0; r < 4; r++) {
        float s = 0, s2 = 0;
#pragma unroll
        for (int t = 0; t < 4; t++) { float h = acc[t][r]; s += h; s2 += h * h; }
        ps[r] = s; pq[r] = s2;
    }
    for (int off = 1; off < 16; off <<= 1) {
#pragma unroll
        for (int r = 0; r < 4; r++) {
            ps[r] += __shfl_xor(ps[r], off, 64);
            pq[r] += __shfl_xor(pq[r], off, 64);
        }
    }
    // epilogue -> sA cols 0..63 (wave-local rows; in-wave LDS dep, no barrier)
#pragma unroll
    for (int r = 0; r < 4; r++) {
        int nb = w * 16 + q * 4 + r;
        float mu = ps[r] * (1.f / 64.f);
        float var = pq[r] * (1.f / 64.f) - mu * mu;
        var = var < 0.f ? 0.f : var;
        float rstd = rsqrtf(var + 1e-5f);
#pragma unroll
        for (int t = 0; t < 4; t++) {
            int colI = t * 16 + ln;
            float hn = (acc[t][r] - mu) * rstd * gcol[t] + btcol[t];
            hn = hn > 0.f ? hn : 0.f;
            float res = layer0 ? (accr[t][r] + brcol[t])
                               : b2f(sA[nb * LPITCH + 64 + colI]);
            sA[nb * LPITCH + colI] = f2b(hn + res);
        }
    }

    if (final_) {
        // FC stage: out = x3 @ w_fc + b_fc; A rows are wave-local (rows w*16+ln)
        f32x4 accf[4] = {{0, 0, 0, 0}, {0, 0, 0, 0}, {0, 0, 0, 0}, {0, 0, 0, 0}};
#pragma unroll
        for (int c = 0; c < 2; c++) {
            bf16x8 a = ld_frag(&aRow[c * 32 + q * 8]);
#pragma unroll
            for (int t = 0; t < 4; t++) {
                bf16x8 b = ld_frag(WfcT + (t * 16 + ln) * 64 + c * 32 + q * 8);
                accf[t] = __builtin_amdgcn_mfma_f32_16x16x32_bf16(a, b, accf[t], 0, 0, 0);
            }
        }
#pragma unroll
        for (int r = 0; r < 4; r++) {
            int node = base + w * 16 + q * 4 + r;
            if (node >= N) continue;
#pragma unroll
            for (int t = 0; t < 4; t++) {
                int colI = t * 16 + ln;
                fout[node * D + colI] = accf[t][r] + bfc[colI];
            }
        }
    } else {
        // coalesced writeback of this wave's 16 rows (2 uint4 per thread)
#pragma unroll
        for (int i = 0; i < 2; i++) {
            int idx = i * 64 + lane;
            int row = w * 16 + (idx >> 3);
            int ch = idx & 7;
            int node = base + row;
            if (node < N)
                *(uint4*)(xb_out + node * D + ch * 8) = *(const uint4*)&sA[row * LPITCH + ch * 8];
        }
    }
}

extern "C" void kernel_launch(void* const* d_in, const int* in_sizes, int n_in,
                              void* d_out, int out_size, void* d_ws, size_t ws_size,
                              hipStream_t stream) {
    const float* x_in = (const float*)d_in[0];
    const int* e_src = (const int*)d_in[1];
    const int* e_dst = (const int*)d_in[2];
    const float* w_l = (const float*)d_in[3];
    const float* b_l = (const float*)d_in[4];
    const float* w_r = (const float*)d_in[5];
    const float* gam = (const float*)d_in[6];
    const float* bet = (const float*)d_in[7];
    const float* w_res = (const float*)d_in[8];
    const float* b_res = (const float*)d_in[9];
    const float* w_fc = (const float*)d_in[10];
    const float* b_fc = (const float*)d_in[11];
    float* out = (float*)d_out;

    const int N = in_sizes[0] / D;
    const int E = in_sizes[1];
    const int nbuck = ((N - 1) >> BSHIFT) + 1;
    const int eper = (E + CHUNKS - 1) / CHUNKS;

    size_t o = 0;
    auto carve = [&](size_t bytes) {
        size_t cur = o;
        o += (bytes + 255) & ~(size_t)255;
        return (char*)d_ws + cur;
    };
    int* row_ptr = (int*)carve((size_t)(N + 1) * 4);
    float* inv_deg = (float*)carve((size_t)N * 4);
    int* colA = (int*)carve((size_t)E * 4);
    int* staging = (int*)carve((size_t)E * 4);
    int* Hh = (int*)carve((size_t)CHUNKS * nbuck * 4);
    int* Orel = (int*)carve((size_t)CHUNKS * nbuck * 4);
    int* Tb = (int*)carve((size_t)nbuck * 4);
    int* baseB = (int*)carve((size_t)(nbuck + 1) * 4);
    u16* WtL = (u16*)carve(3 * 64 * 128 * 2);
    u16* WresT = (u16*)carve(64 * 64 * 2);
    u16* WfcT = (u16*)carve(64 * 64 * 2);
    u16* xbA = (u16*)carve((size_t)N * D * 2);
    u16* xbB = (u16*)carve((size_t)N * D * 2);

    // single cooperative kernel: CSR build + cvt + weight prep
    CsrArgs args;
    args.dst = e_dst;
    args.src = e_src;
    args.E = E;
    args.N = N;
    args.nbuck = nbuck;
    args.eper = eper;
    args.total4 = N * D / 4;
    args.H = Hh;
    args.Orel = Orel;
    args.T = Tb;
    args.base = baseB;
    args.row_ptr = row_ptr;
    args.inv_deg = inv_deg;
    args.staging = staging;
    args.col = colA;
    args.xf = x_in;
    args.wl = w_l;
    args.wr = w_r;
    args.wres = w_res;
    args.wfc = w_fc;
    args.xb = xbA;
    args.WtL = WtL;
    args.WresT = WresT;
    args.WfcT = WfcT;
    void* kargs[] = {&args};
    hipLaunchCooperativeKernel((const void*)csr_kernel, dim3(CHUNKS), dim3(256),
                               kargs, 0, stream);

    int gridT = (N + 63) / 64;

    // layer 0: xbA -> xbB  (residual via w_res MFMA)
    layer_kernel<<<gridT, 256, 0, stream>>>(xbA, row_ptr, colA, inv_deg, WtL,
                                            b_l, gam, bet, WresT, b_res,
                                            WfcT, b_fc, xbB, out, N, 1, 0);
    // layer 1: xbB -> xbA
    layer_kernel<<<gridT, 256, 0, stream>>>(xbB, row_ptr, colA, inv_deg, WtL + 8192,
                                            b_l + 64, gam + 64, bet + 64, WresT, b_res,
                                            WfcT, b_fc, xbA, out, N, 0, 0);
    // layer 2 + fused fc: xbA -> out (f32)
    layer_kernel<<<gridT, 256, 0, stream>>>(xbA, row_ptr, colA, inv_deg, WtL + 16384,
                                            b_l + 128, gam + 128, bet + 128, WresT, b_res,
                                            WfcT, b_fc, xbB, out, N, 0, 1);
}

// Round 12
// 281.092 us; speedup vs baseline: 1.5484x; 1.5484x over previous
//
#include <hip/hip_runtime.h>

typedef unsigned short u16;
typedef __bf16 bf16x8 __attribute__((ext_vector_type(8)));
typedef float f32x4 __attribute__((ext_vector_type(4)));

#define D 64
#define LPITCH 136   // 128 + 8 bf16 pad
#define CHUNKS 256   // edge-array partitions
#define BSHIFT 9     // 512 nodes per bucket (nbuck <= 256 for N <= 131072)
#define CCAP 1280    // LDS edge-list capacity per 64-node tile (mean ~1024, +2 sigma)

__device__ __forceinline__ float b2f(u16 u) {
    unsigned v = ((unsigned)u) << 16;
    float f;
    __builtin_memcpy(&f, &v, 4);
    return f;
}
__device__ __forceinline__ float u2f_lo(unsigned u) {
    unsigned v = u << 16;
    float f;
    __builtin_memcpy(&f, &v, 4);
    return f;
}
__device__ __forceinline__ float u2f_hi(unsigned u) {
    unsigned v = u & 0xFFFF0000u;
    float f;
    __builtin_memcpy(&f, &v, 4);
    return f;
}
__device__ __forceinline__ u16 f2b(float f) {
    unsigned u;
    __builtin_memcpy(&u, &f, 4);
    u = u + 0x7FFFu + ((u >> 16) & 1u);   // RNE
    return (u16)(u >> 16);
}
__device__ __forceinline__ bf16x8 ld_frag(const u16* p) {
    union { uint4 u; bf16x8 b; } cv;
    cv.u = *(const uint4*)p;
    return cv.b;
}

// ---------------- binA: per-chunk bucket histogram + cvt/weight-prep tail ----------
__global__ __launch_bounds__(256) void binA_kernel(const int* __restrict__ dst, int E,
                                                   int* __restrict__ H, int nbuck, int eper,
                                                   const float* __restrict__ xf,
                                                   u16* __restrict__ xb, int total4,
                                                   const float* __restrict__ wl,
                                                   const float* __restrict__ wr,
                                                   const float* __restrict__ wres,
                                                   const float* __restrict__ wfc,
                                                   u16* __restrict__ WtL,
                                                   u16* __restrict__ WresT,
                                                   u16* __restrict__ WfcT,
                                                   int* __restrict__ row_ptr, int N) {
    __shared__ int hist[256];
    int t = threadIdx.x;
    int c = blockIdx.x;
    hist[t] = 0;
    __syncthreads();
    {
        int beg = c * eper, end = min(beg + eper, E);
        for (int i = beg + t; i < end; i += 256)
            atomicAdd(&hist[dst[i] >> BSHIFT], 1);
    }
    __syncthreads();
    if (t < nbuck) H[c * nbuck + t] = hist[t];

    // ---- tails (consumed only by later dispatches; no sync needed) ----
    int gid = c * 256 + t;
    int gstr = CHUNKS * 256;
    if (gid == 0) row_ptr[N] = E;
    for (int i = gid; i < total4; i += gstr) {
        float4 v = *(const float4*)(xf + i * 4);
        ushort4 o;
        o.x = f2b(v.x); o.y = f2b(v.y); o.z = f2b(v.z); o.w = f2b(v.w);
        *(ushort4*)(xb + i * 4) = o;
    }
    for (int idx = gid; idx < 3 * 64 * 128; idx += gstr) {
        int l = idx >> 13;
        int rem = idx & 8191;
        int n = rem >> 7;
        int k = rem & 127;
        float v = (k < 64) ? wl[l * 4096 + k * 64 + n] : wr[l * 4096 + (k - 64) * 64 + n];
        WtL[idx] = f2b(v);
    }
    for (int idx = gid; idx < 4096; idx += gstr) {
        int n = idx >> 6, k = idx & 63;
        WresT[idx] = f2b(wres[k * 64 + n]);
        WfcT[idx] = f2b(wfc[k * 64 + n]);
    }
}

// ---------------- binS2: per-bucket scan over chunk counts -> Orel + T[b] -----------
__global__ __launch_bounds__(256) void binS2_kernel(const int* __restrict__ H,
                                                    int* __restrict__ Orel,
                                                    int* __restrict__ T,
                                                    int nbuck) {
    __shared__ int ss[256];
    int b = blockIdx.x;
    int t = threadIdx.x;
    int h = H[t * nbuck + b];
    ss[t] = h;
    __syncthreads();
    for (int off = 1; off < 256; off <<= 1) {
        int v = (t >= off) ? ss[t - off] : 0;
        __syncthreads();
        ss[t] += v;
        __syncthreads();
    }
    Orel[t * nbuck + b] = ss[t] - h;   // exclusive
    if (t == 255) T[b] = ss[255];
}

// ---------------- binB: scatter packed words; bucket bases from local T-scan --------
__global__ __launch_bounds__(256) void binB_kernel(const int* __restrict__ src,
                                                   const int* __restrict__ dst, int E,
                                                   const int* __restrict__ T,
                                                   const int* __restrict__ Orel,
                                                   int* __restrict__ staging,
                                                   int nbuck, int eper) {
    __shared__ int sc[256];
    int t = threadIdx.x;
    int c = blockIdx.x;
    int v = (t < nbuck) ? T[t] : 0;
    sc[t] = v;
    __syncthreads();
    for (int off = 1; off < 256; off <<= 1) {
        int u = (t >= off) ? sc[t - off] : 0;
        __syncthreads();
        sc[t] += u;
        __syncthreads();
    }
    int baseT = sc[t] - v;              // exclusive bucket base
    int porel = (t < nbuck) ? Orel[c * nbuck + t] : 0;
    __syncthreads();
    sc[t] = baseT + porel;              // per-(chunk,bucket) write cursor
    __syncthreads();
    int beg = c * eper, end = min(beg + eper, E);
    const int mask = (1 << BSHIFT) - 1;
    for (int i = beg + t; i < end; i += 256) {
        int d = dst[i];
        int b = d >> BSHIFT;
        int p = atomicAdd(&sc[b], 1);
        staging[p] = src[i] | ((d & mask) << 17);
    }
}

// ---------------- binC: per-bucket degree hist + scan + col scatter (LDS only) ------
__global__ __launch_bounds__(256) void binC_kernel(const int* __restrict__ staging,
                                                   const int* __restrict__ T,
                                                   int* __restrict__ row_ptr,
                                                   float* __restrict__ inv_deg,
                                                   int* __restrict__ col, int N, int nbuck) {
    __shared__ int cnt[512];
    __shared__ int lrp[512];
    __shared__ int sm[256];
    __shared__ int span[2];
    int b = blockIdx.x;
    int t = threadIdx.x;
    // bucket base via local scan of T
    int v = (t < nbuck) ? T[t] : 0;
    sm[t] = v;
    __syncthreads();
    for (int off = 1; off < 256; off <<= 1) {
        int u = (t >= off) ? sm[t - off] : 0;
        __syncthreads();
        sm[t] += u;
        __syncthreads();
    }
    if (t == b) { span[0] = sm[t] - v; span[1] = sm[t]; }
    cnt[t] = 0;
    cnt[t + 256] = 0;
    __syncthreads();
    int sbeg = span[0], send = span[1];
    int node0 = b << BSHIFT;
    int nn = min(1 << BSHIFT, N - node0);
    for (int i = sbeg + t; i < send; i += 256)
        atomicAdd(&cnt[staging[i] >> 17], 1);
    __syncthreads();
    int c0 = cnt[2 * t], c1 = cnt[2 * t + 1];
    sm[t] = c0 + c1;
    __syncthreads();
    for (int off = 1; off < 256; off <<= 1) {
        int u = (t >= off) ? sm[t - off] : 0;
        __syncthreads();
        sm[t] += u;
        __syncthreads();
    }
    int excl = sm[t] - c0 - c1;
    lrp[2 * t] = excl;
    lrp[2 * t + 1] = excl + c0;
    __syncthreads();
    for (int i = t; i < nn; i += 256) {
        row_ptr[node0 + i] = sbeg + lrp[i];
        int dd = cnt[i];
        inv_deg[node0 + i] = dd > 0 ? 1.0f / (float)dd : 0.0f;
    }
    __syncthreads();
    for (int i = sbeg + t; i < send; i += 256) {
        int word = staging[i];
        int ld = word >> 17;
        int k = atomicSub(&cnt[ld], 1) - 1;
        col[sbeg + lrp[ld] + k] = word & 0x1FFFF;
    }
}

// ---------------- fused SAGE layer: gather-mean + GEMM + LN + ReLU + residual --------
// R9 static-slot gather (best measured) + tile edge-list staged to LDS (lcol):
// the tile's col range [rp[0],rp[64]) is contiguous -> coalesced load, then gather
// reads indices from LDS instead of dependent global col loads. Fallback to global
// col for the rare tile with >CCAP edges (uniform branch).
__global__ __launch_bounds__(256, 4) void layer_kernel(const u16* __restrict__ xb_in,
                                                       const int* __restrict__ row_ptr,
                                                       const int* __restrict__ col,
                                                       const float* __restrict__ inv_deg,
                                                       const u16* __restrict__ Wt,    // [64][128]
                                                       const float* __restrict__ bl,
                                                       const float* __restrict__ gam,
                                                       const float* __restrict__ bet,
                                                       const u16* __restrict__ WresT, // [64][64]
                                                       const float* __restrict__ bres,
                                                       const u16* __restrict__ WfcT,  // [64][64]
                                                       const float* __restrict__ bfc,
                                                       u16* __restrict__ xb_out,
                                                       float* __restrict__ fout,
                                                       int N, int layer0, int final_) {
    __shared__ __align__(16) u16 sA[64 * LPITCH];
    __shared__ __align__(16) u16 sB[64 * LPITCH];   // weights; reused as f32 stage in final
    __shared__ int lcol[CCAP];
    __shared__ int rp[65];
    __shared__ float ideg[64];
    int tid = threadIdx.x;
    int base = blockIdx.x * 64;
    int lane = tid & 63;
    int w = tid >> 6;

    // stage B (W^T rows), 4 uint4 per thread
#pragma unroll
    for (int i = 0; i < 4; i++) {
        int idx = i * 256 + tid;
        int r = idx >> 4, c = idx & 15;
        *(uint4*)&sB[r * LPITCH + c * 8] = *(const uint4*)(Wt + idx * 8);
    }
    // stage x rows into sA cols 64..127, 2 uint4 per thread
#pragma unroll
    for (int i = 0; i < 2; i++) {
        int idx = i * 256 + tid;
        int r = idx >> 3, c = idx & 7;
        int node = base + r;
        uint4 v = make_uint4(0, 0, 0, 0);
        if (node < N) v = *(const uint4*)(xb_in + node * D + c * 8);
        *(uint4*)&sA[r * LPITCH + 64 + c * 8] = v;
    }
    if (tid < 65) rp[tid] = row_ptr[min(base + tid, N)];
    if (tid < 64) ideg[tid] = (base + tid < N) ? inv_deg[base + tid] : 0.f;
    __syncthreads();

    int e0 = rp[0];
    int tileE = rp[64] - e0;
    bool fits = tileE <= CCAP;
    if (fits) {
        for (int i = tid; i < tileE; i += 256) lcol[i] = col[e0 + i];
    }
    __syncthreads();

    // gather stage: slot-per-node, 2 rounds x 8 slots per wave = 16 nodes/wave
    int slot = lane >> 3;
    int chunk = lane & 7;
    auto run_gather = [&](auto LD) {
#pragma unroll
        for (int r = 0; r < 2; r++) {
            int node_l = w * 16 + r * 8 + slot;
            float a0 = 0, a1 = 0, a2 = 0, a3 = 0, a4 = 0, a5 = 0, a6 = 0, a7 = 0;
            int e = rp[node_l], end = rp[node_l + 1];
#define ACC(v)                                          \
    a0 += u2f_lo(v.x); a1 += u2f_hi(v.x);               \
    a2 += u2f_lo(v.y); a3 += u2f_hi(v.y);               \
    a4 += u2f_lo(v.z); a5 += u2f_hi(v.z);               \
    a6 += u2f_lo(v.w); a7 += u2f_hi(v.w);
            for (; e + 7 < end; e += 8) {
                int s0 = LD(e),     s1 = LD(e + 1), s2 = LD(e + 2), s3 = LD(e + 3);
                int s4 = LD(e + 4), s5 = LD(e + 5), s6 = LD(e + 6), s7 = LD(e + 7);
                uint4 v0 = *(const uint4*)(xb_in + s0 * D + chunk * 8);
                uint4 v1 = *(const uint4*)(xb_in + s1 * D + chunk * 8);
                uint4 v2 = *(const uint4*)(xb_in + s2 * D + chunk * 8);
                uint4 v3 = *(const uint4*)(xb_in + s3 * D + chunk * 8);
                uint4 v4 = *(const uint4*)(xb_in + s4 * D + chunk * 8);
                uint4 v5 = *(const uint4*)(xb_in + s5 * D + chunk * 8);
                uint4 v6 = *(const uint4*)(xb_in + s6 * D + chunk * 8);
                uint4 v7 = *(const uint4*)(xb_in + s7 * D + chunk * 8);
                ACC(v0) ACC(v1) ACC(v2) ACC(v3)
                ACC(v4) ACC(v5) ACC(v6) ACC(v7)
            }
            if (e + 3 < end) {
                int s0 = LD(e), s1 = LD(e + 1), s2 = LD(e + 2), s3 = LD(e + 3);
                uint4 v0 = *(const uint4*)(xb_in + s0 * D + chunk * 8);
                uint4 v1 = *(const uint4*)(xb_in + s1 * D + chunk * 8);
                uint4 v2 = *(const uint4*)(xb_in + s2 * D + chunk * 8);
                uint4 v3 = *(const uint4*)(xb_in + s3 * D + chunk * 8);
                ACC(v0) ACC(v1) ACC(v2) ACC(v3)
                e += 4;
            }
            if (e + 1 < end) {
                int s0 = LD(e), s1 = LD(e + 1);
                uint4 v0 = *(const uint4*)(xb_in + s0 * D + chunk * 8);
                uint4 v1 = *(const uint4*)(xb_in + s1 * D + chunk * 8);
                ACC(v0) ACC(v1)
                e += 2;
            }
            if (e < end) {
                int s0 = LD(e);
                uint4 v0 = *(const uint4*)(xb_in + s0 * D + chunk * 8);
                ACC(v0)
            }
#undef ACC
            float m = ideg[node_l];
            uint4 o;
            o.x = (unsigned)f2b(a0 * m) | ((unsigned)f2b(a1 * m) << 16);
            o.y = (unsigned)f2b(a2 * m) | ((unsigned)f2b(a3 * m) << 16);
            o.z = (unsigned)f2b(a4 * m) | ((unsigned)f2b(a5 * m) << 16);
            o.w = (unsigned)f2b(a6 * m) | ((unsigned)f2b(a7 * m) << 16);
            *(uint4*)&sA[node_l * LPITCH + chunk * 8] = o;
        }
    };
    if (fits) run_gather([&](int e) { return lcol[e - e0]; });
    else      run_gather([&](int e) { return col[e]; });
    __syncthreads();

    // GEMM stage
    int q = lane >> 4;
    int ln = lane & 15;
    f32x4 acc[4] = {{0, 0, 0, 0}, {0, 0, 0, 0}, {0, 0, 0, 0}, {0, 0, 0, 0}};
    f32x4 accr[4] = {{0, 0, 0, 0}, {0, 0, 0, 0}, {0, 0, 0, 0}, {0, 0, 0, 0}};
    const u16* aRow = &sA[(w * 16 + ln) * LPITCH];

#pragma unroll
    for (int c = 0; c < 4; c++) {       // K = 128
        bf16x8 a = ld_frag(&aRow[c * 32 + q * 8]);
#pragma unroll
        for (int t = 0; t < 4; t++) {
            bf16x8 b = ld_frag(&sB[(t * 16 + ln) * LPITCH + c * 32 + q * 8]);
            acc[t] = __builtin_amdgcn_mfma_f32_16x16x32_bf16(a, b, acc[t], 0, 0, 0);
        }
    }
    if (layer0) {                       // residual = x @ w_res (one-shot global loads)
#pragma unroll
        for (int c = 0; c < 2; c++) {
            bf16x8 a = ld_frag(&aRow[64 + c * 32 + q * 8]);
#pragma unroll
            for (int t = 0; t < 4; t++) {
                bf16x8 b = ld_frag(WresT + (t * 16 + ln) * 64 + c * 32 + q * 8);
                accr[t] = __builtin_amdgcn_mfma_f32_16x16x32_bf16(a, b, accr[t], 0, 0, 0);
            }
        }
    }

    float bcol[4], gcol[4], btcol[4], brcol[4];
#pragma unroll
    for (int t = 0; t < 4; t++) {
        int colI = t * 16 + ln;
        bcol[t] = bl[colI];
        gcol[t] = gam[colI];
        btcol[t] = bet[colI];
        brcol[t] = layer0 ? bres[colI] : 0.f;
    }
#pragma unroll
    for (int t = 0; t < 4; t++)
#pragma unroll
        for (int r = 0; r < 4; r++) acc[t][r] += bcol[t];

    float ps[4], pq[4];
#pragma unroll
    for (int r = 0; r < 4; r++) {
        float s = 0, s2 = 0;
#pragma unroll
        for (int t = 0; t < 4; t++) { float h = acc[t][r]; s += h; s2 += h * h; }
        ps[r] = s; pq[r] = s2;
    }
    for (int off = 1; off < 16; off <<= 1) {
#pragma unroll
        for (int r = 0; r < 4; r++) {
            ps[r] += __shfl_xor(ps[r], off, 64);
            pq[r] += __shfl_xor(pq[r], off, 64);
        }
    }
    // epilogue -> sA cols 0..63 (wave-local rows; in-wave LDS dep, no barrier)
#pragma unroll
    for (int r = 0; r < 4; r++) {
        int nb = w * 16 + q * 4 + r;
        float mu = ps[r] * (1.f / 64.f);
        float var = pq[r] * (1.f / 64.f) - mu * mu;
        var = var < 0.f ? 0.f : var;
        float rstd = rsqrtf(var + 1e-5f);
#pragma unroll
        for (int t = 0; t < 4; t++) {
            int colI = t * 16 + ln;
            float hn = (acc[t][r] - mu) * rstd * gcol[t] + btcol[t];
            hn = hn > 0.f ? hn : 0.f;
            float res = layer0 ? (accr[t][r] + brcol[t])
                               : b2f(sA[nb * LPITCH + 64 + colI]);
            sA[nb * LPITCH + colI] = f2b(hn + res);
        }
    }

    if (final_) {
        // FC: out = x3 @ w_fc + b_fc; stage f32 through sB (dead after GEMM) for
        // coalesced float4 writeback. Pitch 68 floats breaks bank aliasing.
        f32x4 accf[4] = {{0, 0, 0, 0}, {0, 0, 0, 0}, {0, 0, 0, 0}, {0, 0, 0, 0}};
#pragma unroll
        for (int c = 0; c < 2; c++) {
            bf16x8 a = ld_frag(&aRow[c * 32 + q * 8]);
#pragma unroll
            for (int t = 0; t < 4; t++) {
                bf16x8 b = ld_frag(WfcT + (t * 16 + ln) * 64 + c * 32 + q * 8);
                accf[t] = __builtin_amdgcn_mfma_f32_16x16x32_bf16(a, b, accf[t], 0, 0, 0);
            }
        }
        __syncthreads();               // all waves done reading sB
        float* fB = (float*)sB;        // 64 rows x pitch 68 = 4352 floats = 17408 B
#pragma unroll
        for (int r = 0; r < 4; r++) {
            int nb = w * 16 + q * 4 + r;
#pragma unroll
            for (int t = 0; t < 4; t++) {
                int colI = t * 16 + ln;
                fB[nb * 68 + colI] = accf[t][r] + bfc[colI];
            }
        }
        __syncthreads();
#pragma unroll
        for (int i = 0; i < 4; i++) {
            int idx = i * 256 + tid;
            int row = idx >> 4, cc = idx & 15;
            int node = base + row;
            if (node < N)
                *(float4*)(fout + node * D + cc * 4) = *(const float4*)&fB[row * 68 + cc * 4];
        }
    } else {
        // coalesced writeback of this wave's 16 rows (2 uint4 per thread)
#pragma unroll
        for (int i = 0; i < 2; i++) {
            int idx = i * 64 + lane;
            int row = w * 16 + (idx >> 3);
            int ch = idx & 7;
            int node = base + row;
            if (node < N)
                *(uint4*)(xb_out + node * D + ch * 8) = *(const uint4*)&sA[row * LPITCH + ch * 8];
        }
    }
}

extern "C" void kernel_launch(void* const* d_in, const int* in_sizes, int n_in,
                              void* d_out, int out_size, void* d_ws, size_t ws_size,
                              hipStream_t stream) {
    const float* x_in = (const float*)d_in[0];
    const int* e_src = (const int*)d_in[1];
    const int* e_dst = (const int*)d_in[2];
    const float* w_l = (const float*)d_in[3];
    const float* b_l = (const float*)d_in[4];
    const float* w_r = (const float*)d_in[5];
    const float* gam = (const float*)d_in[6];
    const float* bet = (const float*)d_in[7];
    const float* w_res = (const float*)d_in[8];
    const float* b_res = (const float*)d_in[9];
    const float* w_fc = (const float*)d_in[10];
    const float* b_fc = (const float*)d_in[11];
    float* out = (float*)d_out;

    const int N = in_sizes[0] / D;
    const int E = in_sizes[1];
    const int nbuck = ((N - 1) >> BSHIFT) + 1;
    const int eper = (E + CHUNKS - 1) / CHUNKS;

    size_t o = 0;
    auto carve = [&](size_t bytes) {
        size_t cur = o;
        o += (bytes + 255) & ~(size_t)255;
        return (char*)d_ws + cur;
    };
    int* row_ptr = (int*)carve((size_t)(N + 1) * 4);
    float* inv_deg = (float*)carve((size_t)N * 4);
    int* colA = (int*)carve((size_t)E * 4);
    int* staging = (int*)carve((size_t)E * 4);
    int* Hh = (int*)carve((size_t)CHUNKS * nbuck * 4);
    int* Orel = (int*)carve((size_t)CHUNKS * nbuck * 4);
    int* Tb = (int*)carve((size_t)nbuck * 4);
    u16* WtL = (u16*)carve(3 * 64 * 128 * 2);
    u16* WresT = (u16*)carve(64 * 64 * 2);
    u16* WfcT = (u16*)carve(64 * 64 * 2);
    u16* xbA = (u16*)carve((size_t)N * D * 2);
    u16* xbB = (u16*)carve((size_t)N * D * 2);

    // CSR build (binned, LDS-atomics only) + fused cvt/weight prep
    binA_kernel<<<CHUNKS, 256, 0, stream>>>(e_dst, E, Hh, nbuck, eper,
                                            x_in, xbA, N * D / 4,
                                            w_l, w_r, w_res, w_fc, WtL, WresT, WfcT,
                                            row_ptr, N);
    binS2_kernel<<<nbuck, 256, 0, stream>>>(Hh, Orel, Tb, nbuck);
    binB_kernel<<<CHUNKS, 256, 0, stream>>>(e_src, e_dst, E, Tb, Orel, staging,
                                            nbuck, eper);
    binC_kernel<<<nbuck, 256, 0, stream>>>(staging, Tb, row_ptr, inv_deg, colA, N, nbuck);

    int gridT = (N + 63) / 64;

    // layer 0: xbA -> xbB  (residual via w_res MFMA)
    layer_kernel<<<gridT, 256, 0, stream>>>(xbA, row_ptr, colA, inv_deg, WtL,
                                            b_l, gam, bet, WresT, b_res,
                                            WfcT, b_fc, xbB, out, N, 1, 0);
    // layer 1: xbB -> xbA
    layer_kernel<<<gridT, 256, 0, stream>>>(xbB, row_ptr, colA, inv_deg, WtL + 8192,
                                            b_l + 64, gam + 64, bet + 64, WresT, b_res,
                                            WfcT, b_fc, xbA, out, N, 0, 0);
    // layer 2 + fused fc: xbA -> out (f32)
    layer_kernel<<<gridT, 256, 0, stream>>>(xbA, row_ptr, colA, inv_deg, WtL + 16384,
                                            b_l + 128, gam + 128, bet + 128, WresT, b_res,
                                            WfcT, b_fc, xbB, out, N, 0, 1);
}